// Round 9
// baseline (2823.799 us; speedup 1.0000x reference)
//
#include <hip/hip_runtime.h>

typedef unsigned int u32;
typedef u32 u32x8 __attribute__((ext_vector_type(8)));

#define TT 2048
#define HD 256
#define G4 1024
#define NT 16
#define START_TAG 14
#define STOP_TAG 15
#define NEGV (-10000.0f)

__device__ __forceinline__ int sdot4e(u32 a, u32 b, int c) {
#if __has_builtin(__builtin_amdgcn_sdot4)
    return __builtin_amdgcn_sdot4((int)a, (int)b, c, false);
#else
    c += (int)(signed char)(a & 255) * (int)(signed char)(b & 255);
    c += (int)(signed char)((a >> 8) & 255) * (int)(signed char)((b >> 8) & 255);
    c += (int)(signed char)((a >> 16) & 255) * (int)(signed char)((b >> 16) & 255);
    c += (int)(signed char)(a >> 24) * (int)(signed char)(b >> 24);
    return c;
#endif
}
__device__ __forceinline__ float sigmf_(float x) { return 1.0f / (1.0f + __expf(-x)); }
__device__ __forceinline__ float tanhf_(float x) {
    float e = __expf(-2.0f * fabsf(x));
    return copysignf((1.0f - e) / (1.0f + e), x);
}

// K0: quantize w_hh to int8, per-row scale. One wave per row; lane packs u32 of
// elems 4*lane..4*lane+3. lane<40 -> register file [dir][1024][40];
// lane>=40 -> LDS file [dir][6][1024][4] (q=(lane-40)>>2, rr=(lane-40)&3).
__global__ __launch_bounds__(256) void pack_q8(const float* whh_f, const float* whh_b,
                                               u32* wreg8, u32* wlds8, float* rowscale) {
    int lane = threadIdx.x & 63;
    int row = blockIdx.x * 4 + (threadIdx.x >> 6);   // 0..2047
    int dir = row >> 10, r = row & 1023;
    const float* w = (dir ? whh_b : whh_f) + (size_t)r * HD + lane * 4;
    float4 v = *((const float4*)w);
    float m = fmaxf(fmaxf(fabsf(v.x), fabsf(v.y)), fmaxf(fabsf(v.z), fabsf(v.w)));
    for (int off = 1; off < 64; off <<= 1) m = fmaxf(m, __shfl_xor(m, off, 64));
    float invs = m > 0.f ? 127.f / m : 0.f;
    int q0 = (int)rintf(v.x * invs), q1 = (int)rintf(v.y * invs);
    int q2 = (int)rintf(v.z * invs), q3 = (int)rintf(v.w * invs);
    u32 pk = (u32)(q0 & 255) | ((u32)(q1 & 255) << 8) |
             ((u32)(q2 & 255) << 16) | ((u32)(q3 & 255) << 24);
    if (lane < 40) {
        wreg8[((size_t)(dir * 1024 + r)) * 40 + lane] = pk;
    } else {
        int q = lane - 40, q6 = q >> 2, rr = q & 3;
        wlds8[(((size_t)(dir * 6 + q6)) * 1024 + r) * 4 + rr] = pk;
    }
    if (lane == 0) rowscale[dir * 1024 + r] = m * (1.0f / (127.f * 64.f));
}

// K1: G[dir][t][r] = dot(embed[sent[t or T-1-t]], w_ih[r]) + b[r]   (f32 exact)
// 16 t-rows per block (acc[16] -> ~35 VGPR demand, safe under any budget).
__global__ __launch_bounds__(256) void input_gemm(const int* sent, const float* embed,
                                                  const float* wih_f, const float* b_f,
                                                  const float* wih_b, const float* b_b,
                                                  float* G) {
    __shared__ float X[16][HD];   // 16KB
    __shared__ int rows[16];
    int tid = threadIdx.x;
    int dir = blockIdx.z;
    int t0 = blockIdx.x * 16;
    if (tid < 16) {
        int tg = t0 + tid;
        rows[tid] = sent[dir ? (TT - 1 - tg) : tg];
    }
    __syncthreads();
    for (int i = 0; i < 16; i++) X[i][tid] = embed[(size_t)rows[i] * HD + tid];
    __syncthreads();
    int r = blockIdx.y * 256 + tid;
    const float* wrow = (dir ? wih_b : wih_f) + (size_t)r * HD;
    float acc[16];
#pragma unroll
    for (int i = 0; i < 16; i++) acc[i] = 0.0f;
    for (int kc = 0; kc < HD / 4; kc++) {
        float4 w4 = ((const float4*)wrow)[kc];
#pragma unroll
        for (int i = 0; i < 16; i++) {
            float4 x4 = *((const float4*)&X[i][kc * 4]);
            acc[i] += w4.x * x4.x + w4.y * x4.y + w4.z * x4.z + w4.w * x4.w;
        }
    }
    float bias = (dir ? b_b : b_f)[r];
    for (int i = 0; i < 16; i++)
        G[((size_t)dir * TT + t0 + i) * G4 + r] = acc[i] + bias;
}

// single-row int8 dot block: W = 8 u32 (32 int8); h2q u32 HB..HB+7 (broadcast).
#define DOTQ1(W, HB)                                          \
    {                                                         \
        uint4 pa = *((const uint4*)&h2q[(HB)]);               \
        acc = sdot4e(W[0], pa.x, acc);                        \
        acc = sdot4e(W[1], pa.y, acc);                        \
        acc = sdot4e(W[2], pa.z, acc);                        \
        acc = sdot4e(W[3], pa.w, acc);                        \
        uint4 pb = *((const uint4*)&h2q[(HB) + 4]);           \
        acc = sdot4e(W[4], pb.x, acc);                        \
        acc = sdot4e(W[5], pb.y, acc);                        \
        acc = sdot4e(W[6], pb.z, acc);                        \
        acc = sdot4e(W[7], pb.w, acc);                        \
    }

// K2: persistent per-direction LSTM recurrence, int8 (v_dot4), 1024 threads =
// 1024 gate rows (gate = tid>>8: i,f,g,o; elem = tid&255). Per row 64 u32:
// 40 in FIVE NAMED u32x8 SSA values (demand ~62 <= the measured 64-grant at
// 1024 thr) + 24 via LDS [6][1024][4] (96KB, b128 reads). 4 waves/SIMD TLP
// hides DS/dep latency (R8's 2-wave version idled ~40% of the step).
// Each gate-wave applies its own activation pre-barrier -> tail has ONE tanh.
__global__ __launch_bounds__(1024)
void lstm_rec(const u32* wreg8, const u32* wlds8, const float* rowscale,
              const float* G, const float* h0, const float* c0, float* H) {
    __shared__ u32 Wl[6 * 1024 * 4];       // 96KB, [6][1024][4]
    __shared__ float act[1024];            // 4KB: activated gates (f,g,o used)
    __shared__ __align__(16) u32 h2q[64];  // 256 int8 of h
    int tid = threadIdx.x;
    int dir = blockIdx.x;
    {   // stage LDS weight slice (linear copy preserves layout)
        const uint4* src = (const uint4*)(wlds8 + (size_t)dir * 6 * 1024 * 4);
        uint4* dst = (uint4*)Wl;
        for (int i = tid; i < 6 * 1024; i += 1024) dst[i] = src[i];
    }
    const u32x8* p = (const u32x8*)(wreg8 + ((size_t)dir * 1024 + tid) * 40);
    u32x8 w0 = p[0], w1 = p[1], w2 = p[2], w3 = p[3], w4 = p[4];
    float cr = rowscale[dir * 1024 + tid];
    int gate = tid >> 8;
    float cst = 0.0f;
    if (tid < 256) {
        cst = c0[dir * HD + tid];
        float hv = h0[dir * HD + tid];
        hv = fminf(fmaxf(hv, -1.984375f), 1.984375f);
        ((signed char*)h2q)[tid] = (signed char)(int)rintf(hv * 64.f);
    }
    __syncthreads();
    const float* Gd = G + (size_t)dir * TT * G4;
    float* Hd = H + (size_t)dir * TT * HD;
    const uint4* Wl4 = (const uint4*)Wl;
    const uint4* h2q4 = (const uint4*)h2q;
    for (int t = 0; t < TT; t++) {
        float g0 = Gd[(size_t)t * G4 + tid];   // issued early, used after dots
        int acc = 0;
        DOTQ1(w0, 0) DOTQ1(w1, 8) DOTQ1(w2, 16) DOTQ1(w3, 24) DOTQ1(w4, 32)
#pragma unroll
        for (int q = 0; q < 6; q++) {          // elems 160..255 from LDS, b128
            uint4 hh = h2q4[10 + q];           // broadcast
            uint4 wa = Wl4[q * 1024 + tid];    // distinct, conflict-free linear
            acc = sdot4e(wa.x, hh.x, acc);
            acc = sdot4e(wa.y, hh.y, acc);
            acc = sdot4e(wa.z, hh.z, acc);
            acc = sdot4e(wa.w, hh.w, acc);
        }
        float e = (float)acc * cr + g0;
        float a = (gate == 2) ? tanhf_(e) : sigmf_(e);   // wave-uniform branch
        if (tid >= 256) act[tid] = a;
        __syncthreads();
        if (tid < 256) {
            float sf = act[256 + tid], tg = act[512 + tid], so = act[768 + tid];
            cst = sf * cst + a * tg;                     // a = sig(i)
            float h = so * tanhf_(cst);
            Hd[(size_t)t * HD + tid] = h;
            ((signed char*)h2q)[tid] = (signed char)(int)rintf(h * 64.f);
        }
        __syncthreads();
    }
}

// K3: feats[t][n] = hf[t]·w_out[n][0:256] + hb_scan[T-1-t]·w_out[n][256:512] + b_out[n]
__global__ __launch_bounds__(256) void feats_kernel(const float* H, const float* w_out,
                                                    const float* b_out, float* feats) {
    int idx = blockIdx.x * blockDim.x + threadIdx.x;
    int t = idx >> 4, n = idx & 15;
    const float* hf = H + (size_t)t * HD;
    const float* hb = H + ((size_t)TT + (TT - 1 - t)) * HD;
    const float* w = w_out + (size_t)n * (2 * HD);
    float a = b_out[n];
    for (int k = 0; k < HD; k += 4) {
        float4 h4 = *((const float4*)&hf[k]);
        float4 w4 = *((const float4*)&w[k]);
        a += h4.x * w4.x + h4.y * w4.y + h4.z * w4.z + h4.w * w4.w;
    }
    for (int k = 0; k < HD; k += 4) {
        float4 h4 = *((const float4*)&hb[k]);
        float4 w4 = *((const float4*)&w[HD + k]);
        a += h4.x * w4.x + h4.y * w4.y + h4.z * w4.z + h4.w * w4.w;
    }
    feats[(size_t)t * NT + n] = a;
}

// K4: Viterbi + backtrack, single wave. Shortened per-step chain: the group
// result vft stays resident in all 4 lanes of group n; each step does ONE
// 4-parallel bpermute gather (fused old broadcast+gather), the xor-1/2
// butterfly lowers to DPP. feats staged via LDS in 256-step chunks.
__global__ __launch_bounds__(64) void viterbi_kernel(const float* feats, const float* trans,
                                                     float* out) {
    __shared__ float fl[4096];              // 16KB: 256 steps x 16 tags
    __shared__ float fvs[NT];
    __shared__ unsigned char bps[TT][NT];   // 32KB
    int lane = threadIdx.x;
    int n = lane >> 2, pg = lane & 3;
    float4 tr4 = *((const float4*)&trans[n * NT + pg * 4]);
    float vft = (n == START_TAG) ? 0.0f : NEGV;   // tag n's fv, replicated in group n
    for (int c = 0; c < TT / 256; c++) {
        float4 st[16];
        const float4* src = (const float4*)(feats + c * 4096);
#pragma unroll
        for (int i = 0; i < 16; i++) st[i] = src[i * 64 + lane];
#pragma unroll
        for (int i = 0; i < 16; i++) *((float4*)&fl[(i * 64 + lane) * 4]) = st[i];
        __syncthreads();
        for (int tt = 0; tt < 256; tt++) {
            int t = c * 256 + tt;
            // gather my quad's prev-tag values (tags pg*4+j live in lanes (pg*4+j)*4)
            float f0 = __shfl(vft, ((pg << 2) + 0) << 2, 64);
            float f1 = __shfl(vft, ((pg << 2) + 1) << 2, 64);
            float f2 = __shfl(vft, ((pg << 2) + 2) << 2, 64);
            float f3 = __shfl(vft, ((pg << 2) + 3) << 2, 64);
            float ft = fl[tt * 16 + n];
            float v = f0 + tr4.x; int bi = pg * 4 + 0;
            float v1 = f1 + tr4.y; if (v1 > v) { v = v1; bi = pg * 4 + 1; }
            float v2 = f2 + tr4.z; if (v2 > v) { v = v2; bi = pg * 4 + 2; }
            float v3 = f3 + tr4.w; if (v3 > v) { v = v3; bi = pg * 4 + 3; }
#pragma unroll
            for (int m = 1; m <= 2; m <<= 1) {   // DPP-speed; first-index tie-break
                float ov = __shfl_xor(v, m, 64);
                int ob = __shfl_xor(bi, m, 64);
                if (ov > v || (ov == v && ob < bi)) { v = ov; bi = ob; }
            }
            if (pg == 0) bps[t][n] = (unsigned char)bi;
            vft = v + ft;                        // tag n's new fv (all 4 lanes)
        }
        __syncthreads();
    }
    if ((lane & 3) == 0) fvs[n] = vft;
    __syncthreads();
    if (lane == 0) {
        float best = -3.0e38f; int bt = 0;
        for (int p = 0; p < NT; p++) {
            float tv = fvs[p] + trans[STOP_TAG * NT + p];
            if (tv > best) { best = tv; bt = p; }
        }
        out[0] = best;
        int tag = bt;
        out[TT] = (float)tag;                  // path[T-1]
        for (int t = TT - 2; t >= 0; t--) {
            tag = bps[t + 1][tag];
            out[1 + t] = (float)tag;
        }
    }
}

extern "C" void kernel_launch(void* const* d_in, const int* in_sizes, int n_in,
                              void* d_out, int out_size, void* d_ws, size_t ws_size,
                              hipStream_t stream) {
    const int* sent = (const int*)d_in[0];
    const float* embed = (const float*)d_in[1];
    const float* wih_f = (const float*)d_in[2];
    const float* whh_f = (const float*)d_in[3];
    const float* b_f = (const float*)d_in[4];
    const float* wih_b = (const float*)d_in[5];
    const float* whh_b = (const float*)d_in[6];
    const float* b_b = (const float*)d_in[7];
    const float* w_out = (const float*)d_in[8];
    const float* b_out = (const float*)d_in[9];
    const float* trans = (const float*)d_in[10];
    const float* h0 = (const float*)d_in[11];
    const float* c0 = (const float*)d_in[12];
    float* out = (float*)d_out;
    char* ws = (char*)d_ws;

    float* G = (float*)(ws);                                    // 16MB
    float* H = (float*)(ws + (size_t)16 * 1024 * 1024);         // 4MB
    float* feats = (float*)(ws + (size_t)20 * 1024 * 1024);     // 128KB
    u32* wreg8 = (u32*)(ws + (size_t)21 * 1024 * 1024);         // 320KB
    u32* wlds8 = (u32*)(ws + (size_t)21 * 1024 * 1024 + 512 * 1024);  // 192KB
    float* rowscale = (float*)(ws + (size_t)22 * 1024 * 1024);  // 8KB

    pack_q8<<<dim3(512), 256, 0, stream>>>(whh_f, whh_b, wreg8, wlds8, rowscale);
    input_gemm<<<dim3(TT / 16, G4 / 256, 2), 256, 0, stream>>>(sent, embed, wih_f, b_f,
                                                               wih_b, b_b, G);
    lstm_rec<<<dim3(2), 1024, 0, stream>>>(wreg8, wlds8, rowscale, G, h0, c0, H);
    feats_kernel<<<dim3(TT * NT / 256), 256, 0, stream>>>(H, w_out, b_out, feats);
    viterbi_kernel<<<dim3(1), 64, 0, stream>>>(feats, trans, out);
}